// Round 16
// baseline (1192.539 us; speedup 1.0000x reference)
//
#include <hip/hip_runtime.h>
#include <cstdint>

typedef float f32x4 __attribute__((ext_vector_type(4)));
typedef __bf16 bf16x8 __attribute__((ext_vector_type(8)));
typedef unsigned short us8 __attribute__((ext_vector_type(8)));
typedef unsigned short us4 __attribute__((ext_vector_type(4)));
typedef unsigned int u32x4 __attribute__((ext_vector_type(4)));

#define T2 126

__device__ __forceinline__ unsigned short f2bf(float x){
  union { float f; uint32_t u; } v; v.f = x;
  return (unsigned short)((v.u + 0x7fffu + ((v.u >> 16) & 1u)) >> 16);
}
__device__ __forceinline__ float bf2f(unsigned short h){
  union { uint32_t u; float f; } v; v.u = ((uint32_t)h) << 16; return v.f;
}
__device__ __forceinline__ f32x4 mfma_bf16(us8 a, us8 b, f32x4 c){
  return __builtin_amdgcn_mfma_f32_16x16x32_bf16(
      __builtin_bit_cast(bf16x8, a), __builtin_bit_cast(bf16x8, b), c, 0, 0, 0);
}
__device__ __forceinline__ float sigm(float x){ return 1.0f / (1.0f + __expf(-x)); }

// XOR-swizzled LDS address for a [rows][512] bf16 tile, 8-short (16B) chunks.
#define HSWZ(row, chunk) ((row) * 512 + ((((chunk) ^ ((row) & 7))) << 3))

// ---------------------------------------------------------------------------
// Pack (1536,512) fp32 weights -> bf16 MFMA B-fragments.
// ---------------------------------------------------------------------------
__global__ void __launch_bounds__(256) pack_w_kernel(const float* __restrict__ w,
                                                     unsigned short* __restrict__ dst){
  int tid = blockIdx.x * 256 + threadIdx.x;     // 0..98303
  int l = tid & 63;
  int tile = tid >> 6;                          // jt*16 + kt
  int kt = tile & 15, jt = tile >> 4;
  int row = jt * 16 + (l & 15);
  int col = kt * 32 + (l >> 4) * 8;
  const float* s = w + (size_t)row * 512 + col;
  unsigned short o[8];
  #pragma unroll
  for (int e = 0; e < 8; e++) o[e] = f2bf(s[e]);
  *(us8*)(dst + (size_t)tid * 8) = *(const us8*)o;
}

// ---------------------------------------------------------------------------
// Fused conv+GELU+GEMM, M-tile = 16 batch rows x 7 timesteps (112 samples).
// gates layout (scan-matched): [tl][grp(32)][slc(8)][g(3)][wT(4)][lr(16)][i(16)]
// -> lane's 4 i-values contiguous: one 8B store per (jj,mt); wave = 512B seg.
// ---------------------------------------------------------------------------
__global__ void __launch_bounds__(512, 1) gates_gemm_kernel(
    const float* __restrict__ frames,
    const float* __restrict__ cw,
    const float* __restrict__ cb,
    const unsigned short* __restrict__ wih_p,
    const float* __restrict__ b_ih,
    unsigned short* __restrict__ gates_c,
    int t0, int Tc){
  __shared__ unsigned short alds[112 * 512];   // 114,688 B
  __shared__ float wl[1024];
  __shared__ float cbl[32];
  int tid = threadIdx.x;
  int grp = blockIdx.x & 31;
  int tlc = blockIdx.x >> 5;
  wl[tid] = cw[tid]; wl[tid + 512] = cw[tid + 512];
  if (tid < 32) cbl[tid] = cb[tid];
  __syncthreads();
  // conv+gelu stage: 1792 tasks = 112 samples x 16 patches
  #pragma unroll
  for (int tk = 0; tk < 4; tk++){
    int task = tid + 512 * tk;
    if (task < 1792){
      int sA = task >> 4, patch = task & 15;
      int t7 = sA >> 4, i = sA & 15;            // sA = t7*16 + i
      int tl = tlc * 7 + t7;
      int b = grp * 16 + i;
      int t = t0 + tl;
      const float* fb = frames + ((size_t)b * 128 + t) * 256;
      int ii = patch >> 2, jj = patch & 3;
      float4 pv[4], cv[4];
      #pragma unroll
      for (int p = 0; p < 4; p++){
        int base = (ii * 4 + p) * 16 + jj * 4;
        pv[p] = *(const float4*)(fb + base);          // prev = frame t
        cv[p] = *(const float4*)(fb + 256 + base);    // curr = frame t+1
      }
      #pragma unroll
      for (int o = 0; o < 32; o++){
        const float* wc = &wl[o * 32];
        float acc = cbl[o];
        #pragma unroll
        for (int p = 0; p < 4; p++){
          acc += cv[p].x * wc[p*4+0] + cv[p].y * wc[p*4+1]
               + cv[p].z * wc[p*4+2] + cv[p].w * wc[p*4+3];
          acc += pv[p].x * wc[16+p*4+0] + pv[p].y * wc[16+p*4+1]
               + pv[p].z * wc[16+p*4+2] + pv[p].w * wc[16+p*4+3];
        }
        float g = 0.5f * acc * (1.0f + erff(acc * 0.70710678118654752f));
        int col = o * 16 + patch;
        alds[HSWZ(sA, col >> 3) + (col & 7)] = f2bf(g);
      }
    }
  }
  __syncthreads();
  int l = tid & 63, w = tid >> 6;   // 8 waves
  int lr = l & 15, lh = l >> 4;
  for (int jg = 0; jg < 3; jg++){
    int jt0 = w * 12 + jg * 4;
    int q4 = w * 3 + jg;            // (jt0+jj)/4 base: 0..23
    int g = q4 >> 3, slcT = q4 & 7;
    f32x4 acc[7][4];
    #pragma unroll
    for (int mt = 0; mt < 7; mt++)
      #pragma unroll
      for (int jj = 0; jj < 4; jj++) acc[mt][jj] = (f32x4){0.f,0.f,0.f,0.f};
    #pragma unroll
    for (int kt = 0; kt < 16; kt++){
      us8 a[7], bfr[4];
      #pragma unroll
      for (int mt = 0; mt < 7; mt++)
        a[mt] = *(const us8*)&alds[HSWZ(mt * 16 + lr, kt * 4 + lh)];
      #pragma unroll
      for (int jj = 0; jj < 4; jj++)
        bfr[jj] = *(const us8*)(wih_p + ((size_t)((jt0 + jj) * 16 + kt) * 512 + l * 8));
      #pragma unroll
      for (int mt = 0; mt < 7; mt++)
        #pragma unroll
        for (int jj = 0; jj < 4; jj++)
          acc[mt][jj] = mfma_bf16(a[mt], bfr[jj], acc[mt][jj]);
    }
    #pragma unroll
    for (int jj = 0; jj < 4; jj++){
      float bias = b_ih[(jt0 + jj) * 16 + lr];
      #pragma unroll
      for (int mt = 0; mt < 7; mt++){
        unsigned short ov[4];
        #pragma unroll
        for (int rr = 0; rr < 4; rr++) ov[rr] = f2bf(acc[mt][jj][rr] + bias);
        size_t idx = (((size_t)(tlc * 7 + mt) * 32 + grp) * 8 + slcT) * 3072
                   + g * 1024 + jj * 256 + lr * 16 + lh * 4;
        *(us4*)(gates_c + idx) = *(const us4*)ov;    // 8B coalesced store
      }
    }
  }
}

// ---------------------------------------------------------------------------
// Per-launch init: hq parity0 = h(0) = 0; tags parity0 = 0, parity1 = invalid.
// ---------------------------------------------------------------------------
__global__ void __launch_bounds__(256) scan_init_kernel(u32x4* __restrict__ hq,
                                                        unsigned short* __restrict__ htag){
  int tid = blockIdx.x * 256 + threadIdx.x;
  int stride = gridDim.x * 256;
  for (int i = tid; i < 32768; i += stride)
    hq[i] = (u32x4){0u, 0u, 0u, 0u};
  for (int i = tid; i < 4096; i += stride){
    htag[i] = 0;
    htag[4096 + i] = 0xFFFFu;
  }
}

// ---------------------------------------------------------------------------
// Weight-stationary persistent GRU scan — round-9 protocol VERBATIM (the
// fastest measured: 627us). Quad-granular sc0+sc1 exchange, per-row u16
// tags, publish(8 quads/row by one wave) -> per-wave vmcnt(0) -> row tag;
// consume: poll 16 tag-quads -> barrier -> stage -> compute -> fused
// deconv emit in the handoff shadow. Only change vs r9: gx loads are
// 3 x 8B us4 (gates layout [g][wT][lr][i], proven in r12-r15).
// ---------------------------------------------------------------------------
__global__ void __launch_bounds__(256, 1) gru_scan_kernel(
    const unsigned short* __restrict__ gates_c,
    const unsigned short* __restrict__ whh_p,
    const float* __restrict__ b_hh,
    u32x4* __restrict__ hq,                // [2][512][64] quads
    unsigned short* __restrict__ htag,     // [2][512][8]
    float* __restrict__ h_state,           // [512][512] fp32 chunk carry
    const float* __restrict__ frames,
    const float* __restrict__ dw,
    const float* __restrict__ db,
    float* __restrict__ out,
    int Tc, int t0){
  __shared__ unsigned short hlds[16 * 512];   // h(s) slab, swizzled
  __shared__ unsigned short hout[16 * 64];    // block's h(s+1) tile
  __shared__ float dwl[512];                  // deconv weights
  const int tid = threadIdx.x;
  const int B = blockIdx.x;
  const int grp = B & 31;                     // batch group 0..31
  const int slc = B >> 5;                     // hidden slice 0..7
  const int l = tid & 63;
  const int w = tid >> 6;                     // wave 0..3
  const int lr = l & 15, lh = l >> 4;
  const int j = slc * 64 + w * 16 + lr;       // hidden col
  const int rowb = grp * 16;                  // batch row base
  const int rloc = lh * 4;                    // + r = local row

  dwl[tid] = dw[tid]; dwl[tid + 256] = dw[tid + 256];
  const float dbias = db[0];

  // persistent weight fragments, pinned via volatile loads
  us8 wr[16], wz[16], wn[16];
  {
    const int jt = slc * 4 + w;
    #pragma unroll
    for (int kt = 0; kt < 16; kt++){
      wr[kt] = *(volatile const us8*)(whh_p + ((size_t)((jt      ) * 16 + kt) * 512 + l * 8));
      wz[kt] = *(volatile const us8*)(whh_p + ((size_t)((jt + 32) * 16 + kt) * 512 + l * 8));
      wn[kt] = *(volatile const us8*)(whh_p + ((size_t)((jt + 64) * 16 + kt) * 512 + l * 8));
    }
  }
  const float bhr = b_hh[j], bhz = b_hh[512 + j], bhn = b_hh[1024 + j];
  float hprev[4];
  if (t0 == 0){
    hprev[0] = hprev[1] = hprev[2] = hprev[3] = 0.0f;
  } else {
    #pragma unroll
    for (int r = 0; r < 4; r++) hprev[r] = h_state[(size_t)(rowb + rloc + r) * 512 + j];
  }

  // fused deconv: emit out[:, so] from hlds (= h(so+1)); residual frames[b][so+1]
  auto emit = [&](int so){
    int row = tid >> 4;                       // sample row 0..15
    int b = rowb + row;
    const float* fr = frames + ((size_t)b * 128 + so + 1) * 256;
    float* ob = out + ((size_t)b * T2 + so) * 256;
    #pragma unroll
    for (int e = 0; e < 2; e++){
      int pi = (tid & 15) * 2 + e;            // 0..31
      int pr = slc * 2 + (pi >> 4), pc = pi & 15;
      int ii = pr >> 2, pp = pr & 3, jj2 = pc >> 2, qq = pc & 3;
      float acc = dbias;
      #pragma unroll
      for (int c = 0; c < 32; c++){
        int ch = c * 16 + ii * 4 + jj2;
        acc += bf2f(hlds[HSWZ(row, ch >> 3) + (ch & 7)]) * dwl[c * 16 + pp * 4 + qq];
      }
      float dlt = tanhf(acc);
      float rv = fr[pr * 16 + pc] + dlt;
      ob[pr * 16 + pc] = fminf(fmaxf(rv, 0.0f), 1.0f);
    }
  };

  // poll row tags for step s (parity s&1), then barrier
  auto poll = [&](int s){
    if (tid < 16){
      const u32x4* tp = (const u32x4*)(htag + ((size_t)(s & 1) * 512 + rowb + tid) * 8);
      unsigned int want = (unsigned)s * 0x00010001u;
      for (;;){
        u32x4 tv;
        asm volatile("global_load_dwordx4 %0, %1, off sc0 sc1\n\ts_waitcnt vmcnt(0)"
                     : "=&v"(tv) : "v"(tp) : "memory");
        if (tv[0] == want && tv[1] == want && tv[2] == want && tv[3] == want) break;
        __builtin_amdgcn_s_sleep(1);
      }
    }
    __syncthreads();
  };

  // stage h(s) slab (16 rows x 64 quads) -> hlds, 4 quads/thread
  auto stage = [&](int s){
    const u32x4* rb = hq + (size_t)(s & 1) * 32768;
    int quad = tid & 63, r0 = tid >> 6;       // r0 0..3
    const u32x4* p0 = rb + ((size_t)(rowb + r0) * 64 + quad);
    const u32x4* p1 = p0 + 4 * 64;
    const u32x4* p2 = p0 + 8 * 64;
    const u32x4* p3 = p0 + 12 * 64;
    u32x4 q0, q1, q2, q3;
    asm volatile(
      "global_load_dwordx4 %0, %4, off sc0 sc1\n\t"
      "global_load_dwordx4 %1, %5, off sc0 sc1\n\t"
      "global_load_dwordx4 %2, %6, off sc0 sc1\n\t"
      "global_load_dwordx4 %3, %7, off sc0 sc1\n\t"
      "s_waitcnt vmcnt(0)"
      : "=&v"(q0), "=&v"(q1), "=&v"(q2), "=&v"(q3)
      : "v"(p0), "v"(p1), "v"(p2), "v"(p3)
      : "memory");
    *(u32x4*)&hlds[HSWZ(r0,      quad)] = q0;
    *(u32x4*)&hlds[HSWZ(r0 + 4,  quad)] = q1;
    *(u32x4*)&hlds[HSWZ(r0 + 8,  quad)] = q2;
    *(u32x4*)&hlds[HSWZ(r0 + 12, quad)] = q3;
    __syncthreads();
  };

  for (int tl = 0; tl < Tc; tl++){
    const int s = t0 + tl;
    // gx loads: 3 x 8B (dense, coalesced 512B/wave); complete under the poll
    const unsigned short* gxp = gates_c
        + ((((size_t)tl * 32 + grp) * 8 + slc) * 3072) + w * 256 + lr * 16 + lh * 4;
    us4 gR = *(const us4*)(gxp);
    us4 gZ = *(const us4*)(gxp + 1024);
    us4 gN = *(const us4*)(gxp + 2048);
    poll(s);                         // also WAR barrier: hlds/hout reuse
    stage(s);
    f32x4 aR = {0.f,0.f,0.f,0.f}, aZ = {0.f,0.f,0.f,0.f}, aN = {0.f,0.f,0.f,0.f};
    #pragma unroll
    for (int kt = 0; kt < 16; kt++){
      us8 a = *(const us8*)&hlds[HSWZ(lr, kt * 4 + lh)];
      aR = mfma_bf16(a, wr[kt], aR);
      aZ = mfma_bf16(a, wz[kt], aZ);
      aN = mfma_bf16(a, wn[kt], aN);
    }
    #pragma unroll
    for (int r = 0; r < 4; r++){
      float rr = sigm(bf2f(gR[r]) + aR[r] + bhr);
      float zz = sigm(bf2f(gZ[r]) + aZ[r] + bhz);
      float nn = tanhf(bf2f(gN[r]) + rr * (aN[r] + bhn));
      float hv = (1.0f - zz) * nn + zz * hprev[r];
      hprev[r] = hv;
      hout[(rloc + r) * 64 + w * 16 + lr] = f2bf(hv);
    }
    __syncthreads();                 // hout ready
    // publish: 8 quad stores per row (one wave owns a row) -> drain -> tag
    if (tid < 128){
      int row = tid >> 3, q = tid & 7;
      u32x4 hv = *(const u32x4*)&hout[row * 64 + q * 8];
      u32x4* dst = hq + ((size_t)(((s + 1) & 1) * 512 + rowb + row) * 64 + slc * 8 + q);
      asm volatile("global_store_dwordx4 %0, %1, off sc0 sc1" :: "v"(dst), "v"(hv) : "memory");
      asm volatile("s_waitcnt vmcnt(0)" ::: "memory");
      if (q == 0){
        unsigned int tg = (unsigned)(s + 1);
        unsigned short* tp = htag + ((size_t)((s + 1) & 1) * 512 + rowb + row) * 8 + slc;
        asm volatile("global_store_short %0, %1, off sc0 sc1" :: "v"(tp), "v"(tg) : "memory");
      }
    }
    // fused deconv for out[:, s-1] — runs in the handoff shadow
    if (s >= 1) emit(s - 1);
  }
  // fp32 carry for next chunk
  #pragma unroll
  for (int r = 0; r < 4; r++)
    h_state[(size_t)(rowb + rloc + r) * 512 + j] = hprev[r];
  // final output t=125 from h(126) (only the last chunk)
  if (t0 + Tc == T2){
    poll(T2);                        // barrier also WAR-protects hlds vs last emit
    stage(T2);
    emit(T2 - 1);
  }
}

extern "C" void kernel_launch(void* const* d_in, const int* in_sizes, int n_in,
                              void* d_out, int out_size, void* d_ws, size_t ws_size,
                              hipStream_t stream) {
  const float* frames   = (const float*)d_in[0];
  const float* conv_w   = (const float*)d_in[1];
  const float* conv_b   = (const float*)d_in[2];
  const float* w_ih     = (const float*)d_in[3];
  const float* w_hh     = (const float*)d_in[4];
  const float* b_ih     = (const float*)d_in[5];
  const float* b_hh     = (const float*)d_in[6];
  const float* deconv_w = (const float*)d_in[7];
  const float* deconv_b = (const float*)d_in[8];
  float* out = (float*)d_out;
  char* ws = (char*)d_ws;

  // fixed: wih_p 1.5M | whh_p 1.5M | h_state 1M | hq 1M | htag 16K
  unsigned short* wih_p   = (unsigned short*)(ws);
  unsigned short* whh_p   = (unsigned short*)(ws + 1572864LL);
  float*          h_state = (float*)         (ws + 3145728LL);
  u32x4*          hq      = (u32x4*)         (ws + 4194304LL);
  unsigned short* htag    = (unsigned short*)(ws + 5242880LL);
  char*           chunkws = ws + 5259264LL;

  // chunked region: gates 1,572,864 B per timestep; Tc must be a multiple
  // of 7 (gemm M-tile = 16 batch x 7 timesteps)
  static const int divs[6] = {126, 63, 42, 21, 14, 7};
  int Tc = 7;
  for (int i = 0; i < 6; i++){
    long long need = 5259264LL + 1572864LL * divs[i];
    if (need <= (long long)ws_size){ Tc = divs[i]; break; }
  }
  int G = T2 / Tc;

  unsigned short* gates_c = (unsigned short*)(chunkws);

  pack_w_kernel<<<384, 256, 0, stream>>>(w_ih, wih_p);
  pack_w_kernel<<<384, 256, 0, stream>>>(w_hh, whh_p);
  scan_init_kernel<<<64, 256, 0, stream>>>(hq, htag);

  for (int c = 0; c < G; c++){
    int t0 = c * Tc;
    gates_gemm_kernel<<<32 * (Tc / 7), 512, 0, stream>>>(frames, conv_w, conv_b, wih_p,
                                                         b_ih, gates_c, t0, Tc);
    gru_scan_kernel<<<256, 256, 0, stream>>>(gates_c, whh_p, b_hh, hq, htag, h_state,
                                             frames, deconv_w, deconv_b, out,
                                             Tc, t0);
  }
}

// Round 17
// 855.454 us; speedup vs baseline: 1.3940x; 1.3940x over previous
//
#include <hip/hip_runtime.h>
#include <cstdint>

typedef float f32x4 __attribute__((ext_vector_type(4)));
typedef __bf16 bf16x8 __attribute__((ext_vector_type(8)));
typedef unsigned short us8 __attribute__((ext_vector_type(8)));
typedef unsigned int u32x4 __attribute__((ext_vector_type(4)));
typedef unsigned long long u64;

#define T2 126

__device__ __forceinline__ unsigned short f2bf(float x){
  union { float f; uint32_t u; } v; v.f = x;
  return (unsigned short)((v.u + 0x7fffu + ((v.u >> 16) & 1u)) >> 16);
}
__device__ __forceinline__ float bf2f(unsigned short h){
  union { uint32_t u; float f; } v; v.u = ((uint32_t)h) << 16; return v.f;
}
__device__ __forceinline__ f32x4 mfma_bf16(us8 a, us8 b, f32x4 c){
  return __builtin_amdgcn_mfma_f32_16x16x32_bf16(
      __builtin_bit_cast(bf16x8, a), __builtin_bit_cast(bf16x8, b), c, 0, 0, 0);
}
__device__ __forceinline__ float sigm(float x){ return 1.0f / (1.0f + __expf(-x)); }

// XOR-swizzled LDS address for a [rows][512] bf16 tile, 8-short (16B) chunks.
#define HSWZ(row, chunk) ((row) * 512 + ((((chunk) ^ ((row) & 7))) << 3))

// ---------------------------------------------------------------------------
// Pack (1536,512) fp32 weights -> bf16 MFMA B-fragments.
// ---------------------------------------------------------------------------
__global__ void __launch_bounds__(256) pack_w_kernel(const float* __restrict__ w,
                                                     unsigned short* __restrict__ dst){
  int tid = blockIdx.x * 256 + threadIdx.x;     // 0..98303
  int l = tid & 63;
  int tile = tid >> 6;                          // jt*16 + kt
  int kt = tile & 15, jt = tile >> 4;
  int row = jt * 16 + (l & 15);
  int col = kt * 32 + (l >> 4) * 8;
  const float* s = w + (size_t)row * 512 + col;
  unsigned short o[8];
  #pragma unroll
  for (int e = 0; e < 8; e++) o[e] = f2bf(s[e]);
  *(us8*)(dst + (size_t)tid * 8) = *(const us8*)o;
}

// ---------------------------------------------------------------------------
// Fused conv+GELU+GEMM, M-tile = 16 batch rows x 7 timesteps (112 samples).
// mt <-> t, lane row (lh*4+r) <-> batch-in-group: C-stores land as wave-
// coalesced 32B segments in the scan-matched gates layout
// [tl][grp(32)][slc(8)][g(3)][wT(4)][i(16)][lr(16)]  (3072 u16 per (tl,grp,slc))
// ---------------------------------------------------------------------------
__global__ void __launch_bounds__(512, 1) gates_gemm_kernel(
    const float* __restrict__ frames,
    const float* __restrict__ cw,
    const float* __restrict__ cb,
    const unsigned short* __restrict__ wih_p,
    const float* __restrict__ b_ih,
    unsigned short* __restrict__ gates_c,
    int t0, int Tc){
  __shared__ unsigned short alds[112 * 512];   // 114,688 B
  __shared__ float wl[1024];
  __shared__ float cbl[32];
  int tid = threadIdx.x;
  int grp = blockIdx.x & 31;
  int tlc = blockIdx.x >> 5;
  wl[tid] = cw[tid]; wl[tid + 512] = cw[tid + 512];
  if (tid < 32) cbl[tid] = cb[tid];
  __syncthreads();
  // conv+gelu stage: 1792 tasks = 112 samples x 16 patches
  #pragma unroll
  for (int tk = 0; tk < 4; tk++){
    int task = tid + 512 * tk;
    if (task < 1792){
      int sA = task >> 4, patch = task & 15;
      int t7 = sA >> 4, i = sA & 15;            // sA = t7*16 + i
      int tl = tlc * 7 + t7;
      int b = grp * 16 + i;
      int t = t0 + tl;
      const float* fb = frames + ((size_t)b * 128 + t) * 256;
      int ii = patch >> 2, jj = patch & 3;
      float4 pv[4], cv[4];
      #pragma unroll
      for (int p = 0; p < 4; p++){
        int base = (ii * 4 + p) * 16 + jj * 4;
        pv[p] = *(const float4*)(fb + base);          // prev = frame t
        cv[p] = *(const float4*)(fb + 256 + base);    // curr = frame t+1
      }
      #pragma unroll
      for (int o = 0; o < 32; o++){
        const float* wc = &wl[o * 32];
        float acc = cbl[o];
        #pragma unroll
        for (int p = 0; p < 4; p++){
          acc += cv[p].x * wc[p*4+0] + cv[p].y * wc[p*4+1]
               + cv[p].z * wc[p*4+2] + cv[p].w * wc[p*4+3];
          acc += pv[p].x * wc[16+p*4+0] + pv[p].y * wc[16+p*4+1]
               + pv[p].z * wc[16+p*4+2] + pv[p].w * wc[16+p*4+3];
        }
        float g = 0.5f * acc * (1.0f + erff(acc * 0.70710678118654752f));
        int col = o * 16 + patch;
        alds[HSWZ(sA, col >> 3) + (col & 7)] = f2bf(g);
      }
    }
  }
  __syncthreads();
  int l = tid & 63, w = tid >> 6;   // 8 waves
  int lr = l & 15, lh = l >> 4;
  for (int jg = 0; jg < 3; jg++){
    int jt0 = w * 12 + jg * 4;
    int q4 = w * 3 + jg;            // jt0/4: 0..23
    int g = q4 >> 3, slcT = q4 & 7;
    f32x4 acc[7][4];
    #pragma unroll
    for (int mt = 0; mt < 7; mt++)
      #pragma unroll
      for (int jj = 0; jj < 4; jj++) acc[mt][jj] = (f32x4){0.f,0.f,0.f,0.f};
    #pragma unroll
    for (int kt = 0; kt < 16; kt++){
      us8 a[7], bfr[4];
      #pragma unroll
      for (int mt = 0; mt < 7; mt++)
        a[mt] = *(const us8*)&alds[HSWZ(mt * 16 + lr, kt * 4 + lh)];
      #pragma unroll
      for (int jj = 0; jj < 4; jj++)
        bfr[jj] = *(const us8*)(wih_p + ((size_t)((jt0 + jj) * 16 + kt) * 512 + l * 8));
      #pragma unroll
      for (int mt = 0; mt < 7; mt++)
        #pragma unroll
        for (int jj = 0; jj < 4; jj++)
          acc[mt][jj] = mfma_bf16(a[mt], bfr[jj], acc[mt][jj]);
    }
    #pragma unroll
    for (int jj = 0; jj < 4; jj++){
      float bias = b_ih[(jt0 + jj) * 16 + lr];
      #pragma unroll
      for (int mt = 0; mt < 7; mt++){
        size_t base2 = (((size_t)(tlc * 7 + mt) * 32 + grp) * 8 + slcT) * 3072
                     + g * 1024 + jj * 256 + lr;
        #pragma unroll
        for (int rr = 0; rr < 4; rr++)
          gates_c[base2 + (lh * 4 + rr) * 16] = f2bf(acc[mt][jj][rr] + bias);
      }
    }
  }
}

// ---------------------------------------------------------------------------
// Per-launch init: hq parity0 = h(0) = 0; tags parity0 = 0, parity1 = invalid.
// ---------------------------------------------------------------------------
__global__ void __launch_bounds__(256) scan_init_kernel(u32x4* __restrict__ hq,
                                                        unsigned short* __restrict__ htag){
  int tid = blockIdx.x * 256 + threadIdx.x;
  int stride = gridDim.x * 256;
  for (int i = tid; i < 32768; i += stride)
    hq[i] = (u32x4){0u, 0u, 0u, 0u};
  for (int i = tid; i < 4096; i += stride){
    htag[i] = 0;
    htag[4096 + i] = 0xFFFFu;
  }
}

// ---------------------------------------------------------------------------
// Weight-stationary persistent GRU scan — round-9 protocol VERBATIM (the
// fastest measured: 627us / 855 total). Quad-granular sc0+sc1 exchange,
// per-row u16 tags: publish 8 quads/row (one wave owns a row) -> per-lane
// vmcnt(0) -> row tag store => tag observed implies data visible.
// Consume: poll 16 tag-quads (8 tags each) -> barrier -> stage quads ->
// LDS -> 48 MFMA -> gate math -> fused deconv emit in the handoff shadow.
// Monotone tags + parity double-buffer => no WAR hazard.
// ---------------------------------------------------------------------------
__global__ void __launch_bounds__(256, 1) gru_scan_kernel(
    const unsigned short* __restrict__ gates_c,
    const unsigned short* __restrict__ whh_p,
    const float* __restrict__ b_hh,
    u32x4* __restrict__ hq,                // [2][512][64] quads
    unsigned short* __restrict__ htag,     // [2][512][8]
    float* __restrict__ h_state,           // [512][512] fp32 chunk carry
    const float* __restrict__ frames,
    const float* __restrict__ dw,
    const float* __restrict__ db,
    float* __restrict__ out,
    int Tc, int t0){
  __shared__ unsigned short hlds[16 * 512];   // h(s) slab, swizzled
  __shared__ unsigned short hout[16 * 64];    // block's h(s+1) tile
  __shared__ float dwl[512];                  // deconv weights
  const int tid = threadIdx.x;
  const int B = blockIdx.x;
  const int grp = B & 31;                     // batch group 0..31
  const int slc = B >> 5;                     // hidden slice 0..7
  const int l = tid & 63;
  const int w = tid >> 6;                     // wave 0..3
  const int lr = l & 15, lh = l >> 4;
  const int j = slc * 64 + w * 16 + lr;       // hidden col
  const int rowb = grp * 16;                  // batch row base
  const int rloc = lh * 4;                    // + r = local row

  dwl[tid] = dw[tid]; dwl[tid + 256] = dw[tid + 256];
  const float dbias = db[0];

  // persistent weight fragments, pinned via volatile loads
  us8 wr[16], wz[16], wn[16];
  {
    const int jt = slc * 4 + w;
    #pragma unroll
    for (int kt = 0; kt < 16; kt++){
      wr[kt] = *(volatile const us8*)(whh_p + ((size_t)((jt      ) * 16 + kt) * 512 + l * 8));
      wz[kt] = *(volatile const us8*)(whh_p + ((size_t)((jt + 32) * 16 + kt) * 512 + l * 8));
      wn[kt] = *(volatile const us8*)(whh_p + ((size_t)((jt + 64) * 16 + kt) * 512 + l * 8));
    }
  }
  const float bhr = b_hh[j], bhz = b_hh[512 + j], bhn = b_hh[1024 + j];
  float hprev[4];
  if (t0 == 0){
    hprev[0] = hprev[1] = hprev[2] = hprev[3] = 0.0f;
  } else {
    #pragma unroll
    for (int r = 0; r < 4; r++) hprev[r] = h_state[(size_t)(rowb + rloc + r) * 512 + j];
  }

  // fused deconv: emit out[:, so] from hlds (= h(so+1)); residual frames[b][so+1]
  auto emit = [&](int so){
    int row = tid >> 4;                       // sample row 0..15
    int b = rowb + row;
    const float* fr = frames + ((size_t)b * 128 + so + 1) * 256;
    float* ob = out + ((size_t)b * T2 + so) * 256;
    #pragma unroll
    for (int e = 0; e < 2; e++){
      int pi = (tid & 15) * 2 + e;            // 0..31
      int pr = slc * 2 + (pi >> 4), pc = pi & 15;
      int ii = pr >> 2, pp = pr & 3, jj2 = pc >> 2, qq = pc & 3;
      float acc = dbias;
      #pragma unroll
      for (int c = 0; c < 32; c++){
        int ch = c * 16 + ii * 4 + jj2;
        acc += bf2f(hlds[HSWZ(row, ch >> 3) + (ch & 7)]) * dwl[c * 16 + pp * 4 + qq];
      }
      float dlt = tanhf(acc);
      float rv = fr[pr * 16 + pc] + dlt;
      ob[pr * 16 + pc] = fminf(fmaxf(rv, 0.0f), 1.0f);
    }
  };

  // poll row tags for step s (parity s&1), then barrier
  auto poll = [&](int s){
    if (tid < 16){
      const u32x4* tp = (const u32x4*)(htag + ((size_t)(s & 1) * 512 + rowb + tid) * 8);
      unsigned int want = (unsigned)s * 0x00010001u;
      for (;;){
        u32x4 tv;
        asm volatile("global_load_dwordx4 %0, %1, off sc0 sc1\n\ts_waitcnt vmcnt(0)"
                     : "=&v"(tv) : "v"(tp) : "memory");
        if (tv[0] == want && tv[1] == want && tv[2] == want && tv[3] == want) break;
        __builtin_amdgcn_s_sleep(1);
      }
    }
    __syncthreads();
  };

  // stage h(s) slab (16 rows x 64 quads) -> hlds, 4 quads/thread
  auto stage = [&](int s){
    const u32x4* rb = hq + (size_t)(s & 1) * 32768;
    int quad = tid & 63, r0 = tid >> 6;       // r0 0..3
    const u32x4* p0 = rb + ((size_t)(rowb + r0) * 64 + quad);
    const u32x4* p1 = p0 + 4 * 64;
    const u32x4* p2 = p0 + 8 * 64;
    const u32x4* p3 = p0 + 12 * 64;
    u32x4 q0, q1, q2, q3;
    asm volatile(
      "global_load_dwordx4 %0, %4, off sc0 sc1\n\t"
      "global_load_dwordx4 %1, %5, off sc0 sc1\n\t"
      "global_load_dwordx4 %2, %6, off sc0 sc1\n\t"
      "global_load_dwordx4 %3, %7, off sc0 sc1\n\t"
      "s_waitcnt vmcnt(0)"
      : "=&v"(q0), "=&v"(q1), "=&v"(q2), "=&v"(q3)
      : "v"(p0), "v"(p1), "v"(p2), "v"(p3)
      : "memory");
    *(u32x4*)&hlds[HSWZ(r0,      quad)] = q0;
    *(u32x4*)&hlds[HSWZ(r0 + 4,  quad)] = q1;
    *(u32x4*)&hlds[HSWZ(r0 + 8,  quad)] = q2;
    *(u32x4*)&hlds[HSWZ(r0 + 12, quad)] = q3;
    __syncthreads();
  };

  for (int tl = 0; tl < Tc; tl++){
    const int s = t0 + tl;
    // gx loads (12 x u16, dense block; complete under the poll)
    const unsigned short* gxp = gates_c
        + ((((size_t)tl * 32 + grp) * 8 + slc) * 3072) + w * 256 + lh * 64 + lr;
    unsigned short gxu[12];
    #pragma unroll
    for (int g = 0; g < 3; g++)
      #pragma unroll
      for (int r = 0; r < 4; r++)
        gxu[g * 4 + r] = gxp[g * 1024 + r * 16];
    poll(s);                         // also WAR barrier: hlds/hout reuse
    stage(s);
    f32x4 aR = {0.f,0.f,0.f,0.f}, aZ = {0.f,0.f,0.f,0.f}, aN = {0.f,0.f,0.f,0.f};
    #pragma unroll
    for (int kt = 0; kt < 16; kt++){
      us8 a = *(const us8*)&hlds[HSWZ(lr, kt * 4 + lh)];
      aR = mfma_bf16(a, wr[kt], aR);
      aZ = mfma_bf16(a, wz[kt], aZ);
      aN = mfma_bf16(a, wn[kt], aN);
    }
    #pragma unroll
    for (int r = 0; r < 4; r++){
      float rr = sigm(bf2f(gxu[r]) + aR[r] + bhr);
      float zz = sigm(bf2f(gxu[4 + r]) + aZ[r] + bhz);
      float nn = tanhf(bf2f(gxu[8 + r]) + rr * (aN[r] + bhn));
      float hv = (1.0f - zz) * nn + zz * hprev[r];
      hprev[r] = hv;
      hout[(rloc + r) * 64 + w * 16 + lr] = f2bf(hv);
    }
    __syncthreads();                 // hout ready
    // publish: 8 quad stores per row (one wave owns a row) -> drain -> tag
    if (tid < 128){
      int row = tid >> 3, q = tid & 7;
      u32x4 hv = *(const u32x4*)&hout[row * 64 + q * 8];
      u32x4* dst = hq + ((size_t)(((s + 1) & 1) * 512 + rowb + row) * 64 + slc * 8 + q);
      asm volatile("global_store_dwordx4 %0, %1, off sc0 sc1" :: "v"(dst), "v"(hv) : "memory");
      asm volatile("s_waitcnt vmcnt(0)" ::: "memory");
      if (q == 0){
        unsigned int tg = (unsigned)(s + 1);
        unsigned short* tp = htag + ((size_t)((s + 1) & 1) * 512 + rowb + row) * 8 + slc;
        asm volatile("global_store_short %0, %1, off sc0 sc1" :: "v"(tp), "v"(tg) : "memory");
      }
    }
    // fused deconv for out[:, s-1] — runs in the handoff shadow
    if (s >= 1) emit(s - 1);
  }
  // fp32 carry for next chunk
  #pragma unroll
  for (int r = 0; r < 4; r++)
    h_state[(size_t)(rowb + rloc + r) * 512 + j] = hprev[r];
  // final output t=125 from h(126) (only the last chunk)
  if (t0 + Tc == T2){
    poll(T2);                        // barrier also WAR-protects hlds vs last emit
    stage(T2);
    emit(T2 - 1);
  }
}

extern "C" void kernel_launch(void* const* d_in, const int* in_sizes, int n_in,
                              void* d_out, int out_size, void* d_ws, size_t ws_size,
                              hipStream_t stream) {
  const float* frames   = (const float*)d_in[0];
  const float* conv_w   = (const float*)d_in[1];
  const float* conv_b   = (const float*)d_in[2];
  const float* w_ih     = (const float*)d_in[3];
  const float* w_hh     = (const float*)d_in[4];
  const float* b_ih     = (const float*)d_in[5];
  const float* b_hh     = (const float*)d_in[6];
  const float* deconv_w = (const float*)d_in[7];
  const float* deconv_b = (const float*)d_in[8];
  float* out = (float*)d_out;
  char* ws = (char*)d_ws;

  // fixed: wih_p 1.5M | whh_p 1.5M | h_state 1M | hq 1M | htag 16K
  unsigned short* wih_p   = (unsigned short*)(ws);
  unsigned short* whh_p   = (unsigned short*)(ws + 1572864LL);
  float*          h_state = (float*)         (ws + 3145728LL);
  u32x4*          hq      = (u32x4*)         (ws + 4194304LL);
  unsigned short* htag    = (unsigned short*)(ws + 5242880LL);
  char*           chunkws = ws + 5259264LL;

  // chunked region: gates 1,572,864 B per timestep; Tc must be a multiple
  // of 7 (gemm M-tile = 16 batch x 7 timesteps)
  static const int divs[6] = {126, 63, 42, 21, 14, 7};
  int Tc = 7;
  for (int i = 0; i < 6; i++){
    long long need = 5259264LL + 1572864LL * divs[i];
    if (need <= (long long)ws_size){ Tc = divs[i]; break; }
  }
  int G = T2 / Tc;

  unsigned short* gates_c = (unsigned short*)(chunkws);

  pack_w_kernel<<<384, 256, 0, stream>>>(w_ih, wih_p);
  pack_w_kernel<<<384, 256, 0, stream>>>(w_hh, whh_p);
  scan_init_kernel<<<64, 256, 0, stream>>>(hq, htag);

  for (int c = 0; c < G; c++){
    int t0 = c * Tc;
    gates_gemm_kernel<<<32 * (Tc / 7), 512, 0, stream>>>(frames, conv_w, conv_b, wih_p,
                                                         b_ih, gates_c, t0, Tc);
    gru_scan_kernel<<<256, 256, 0, stream>>>(gates_c, whh_p, b_hh, hq, htag, h_state,
                                             frames, deconv_w, deconv_b, out,
                                             Tc, t0);
  }
}